// Round 1
// baseline (145.645 us; speedup 1.0000x reference)
//
#include <hip/hip_runtime.h>

// SingleStageDetector, R10 = R9 restructured for occupancy/phase-overlap:
// 16 hw-rows per block (was 32) -> 40 KB LDS -> 4 blocks/CU (32 waves, 100%
// occupancy cap), grid 1024 = 4 phase-staggered blocks/CU so staging (HBM)
// overlaps K-loop (LDS/MFMA) and IoU (VALU) of neighbors. Staging writes are
// now bank-conflict-free (wave = 4 consecutive cp x 16 rows -> 32 banks x 2).
// Structure otherwise identical to proven R8/R9: prep_w (W1/W2 -> frag images
// in ws) + fused_main: stage F 16-hw slice -> LDS (bf16-pair, XOR-swizzled)
// -> barrier-free 40-step MFMA K-loop (A global frags, 2-deep prefetch)
// -> h (bias+leaky) -> aliased LDS -> GEMM2 (5 tiles, waves 0-4) + epilogue
// -> register IoU (waves 5-7 start it early).

#define CIN_  1280
#define HW_   49
#define HID_  128
#define OUTD_ 65
#define NGT_  40
#define NP_   441

// flat output offsets (elements), reference return order
#define CONF_OFF 0
#define OFFS_OFF 112896   // 256*9*49
#define CLS_OFF  564480   // + 256*9*4*49
#define IOU_OFF  815360   // + 256*20*49 ; total 5,331,200

// ws layout (u32): W1f frags ((K32*8+mt)*64+lane)*4+sub, then W2f frags
#define WS_W1F_U32 81920u
#define WS_W2F_U32 5120u

typedef __bf16 bf16x8 __attribute__((ext_vector_type(8)));
typedef float  f32x4  __attribute__((ext_vector_type(4)));

__device__ __forceinline__ unsigned pack2bf(float lo, float hi) {
    unsigned a = __float_as_uint(lo);
    unsigned b = __float_as_uint(hi);
    a = (a + 0x7FFFu + ((a >> 16) & 1u)) >> 16;   // RNE f32->bf16
    b = (b + 0x7FFFu + ((b >> 16) & 1u)) >> 16;
    return a | (b << 16);
}
__device__ __forceinline__ float sigmoidf_(float v) { return 1.f / (1.f + __expf(-v)); }

__device__ __forceinline__ bf16x8 ld_frag(const unsigned* p) {
    union { uint4 u; bf16x8 v; } x;
    x.u = *(const uint4*)p;                       // 16B-aligned ds_read_b128
    return x.v;
}
__device__ __forceinline__ bf16x8 as_bf(uint4 u) {
    union { uint4 u; bf16x8 v; } x; x.u = u; return x.v;
}

// ---------------------------------------------------------------------------
// prep_w: W1 (128,1280) + W2 (65,128) -> fragment-ready bf16 images. (R8.)
// ---------------------------------------------------------------------------
__global__ __launch_bounds__(256) void prep_w(
    const float* __restrict__ W1, const float* __restrict__ W2,
    unsigned* __restrict__ ws)
{
    int X = blockIdx.x * 256 + threadIdx.x;       // 0..87039
    if (X < (int)WS_W1F_U32) {
        int sub = X & 3, lane = (X >> 2) & 63, f = X >> 8;
        int mt = f & 7, K32 = f >> 3;
        int o = mt * 16 + (lane & 15);
        int c = K32 * 32 + (lane >> 4) * 8 + sub * 2;
        float2 v = *(const float2*)(W1 + o * CIN_ + c);
        ws[X] = pack2bf(v.x, v.y);
    } else {
        int Y = X - (int)WS_W1F_U32;              // 0..5119
        int sub = Y & 3, lane = (Y >> 2) & 63, f = Y >> 8;
        int mt2 = f % 5, ks2 = f / 5;
        int o2 = mt2 * 16 + (lane & 15);
        int c = ks2 * 32 + (lane >> 4) * 8 + sub * 2;
        unsigned val = 0;
        if (o2 < OUTD_) {
            float2 v = *(const float2*)(W2 + o2 * HID_ + c);
            val = pack2bf(v.x, v.y);
        }
        ws[WS_W1F_U32 + Y] = val;
    }
}

// ---------------------------------------------------------------------------
// fused_main: block = (b, qtr). LDS: smF 16 rows x 640 u32 (40,960 B), XOR
// swizzle on 16B slots (phys_cb = cb ^ (row&7)). smHT (16x68 u32) aliases smF.
// 4 blocks/CU resident.
// ---------------------------------------------------------------------------
__global__ __launch_bounds__(512, 8) void fused_main(
    const float* __restrict__ F,     // (256,1280,7,7)
    const float* __restrict__ grd,   // (256,7,7,2)
    const float* __restrict__ bbox,  // (256,40,5)
    const float* __restrict__ anc,   // (9,2)
    const unsigned* __restrict__ wsW,
    const float* __restrict__ B1,    // (128,)
    const float* __restrict__ B2,    // (65,)
    float* __restrict__ out)
{
    __shared__ __align__(16) unsigned lds[16 * 640];   // 40,960 B
    unsigned* smHT = lds;                              // aliased after K-loop

    const int tid  = threadIdx.x;
    const int b    = blockIdx.x >> 2;
    const int qtr  = blockIdx.x & 3;
    const int lane = tid & 63;
    const int w    = tid >> 6;         // 0..7 = GEMM1 m-tile
    const int quad = lane >> 4;
    const int m16  = lane & 15;
    const int hw0  = qtr * 16;

    const float* Fb = F + b * (CIN_ * HW_);

    // ---- stage F hw-slice: 4 groups x (10 loads -> 5 writes) ----
    // i = it*512+tid -> cp = i>>4 (0..639), row = i&15, hw = hw0+row.
    // Pad rows (hw>=49) -> zeros. Wave writes: 4 consecutive cp (same cb,
    // sub 0..3) x 16 rows -> 32 distinct banks x 2 lanes: conflict-free.
    #pragma unroll
    for (int g = 0; g < 4; ++g) {
        float f0[5], f1[5];
        #pragma unroll
        for (int u = 0; u < 5; ++u) {
            int i   = (g * 5 + u) * 512 + tid;
            int cp  = i >> 4;
            int row = i & 15;
            int hw  = hw0 + row;
            bool ok = hw < HW_;
            f0[u] = ok ? Fb[(2 * cp) * HW_ + hw] : 0.f;
            f1[u] = ok ? Fb[(2 * cp + 1) * HW_ + hw] : 0.f;
        }
        #pragma unroll
        for (int u = 0; u < 5; ++u) {
            int i   = (g * 5 + u) * 512 + tid;
            int cp  = i >> 4;
            int row = i & 15;
            int cb = cp >> 2, sub = cp & 3;
            lds[row * 640 + ((cb ^ (row & 7)) << 2) + sub] = pack2bf(f0[u], f1[u]);
        }
    }
    __syncthreads();

    // ---- GEMM1 K-loop: 40 steps, barrier-free, 2-deep A prefetch ----
    const uint4* Ap = (const uint4*)wsW + w * 64 + lane;   // + K32*8*64
    const unsigned* r0b = lds + m16 * 640;
    const int swz = (m16 & 7);

    f32x4 acc0 = (f32x4)(0.f);
    uint4 a0 = Ap[0];
    uint4 a1 = Ap[512];
    for (int k = 0; k < 40; ++k) {
        uint4 an;
        if (k < 38) an = Ap[(k + 2) * 512];                // prefetch k+2
        int off = ((k * 4 + quad) ^ swz) << 2;
        acc0 = __builtin_amdgcn_mfma_f32_16x16x32_bf16(as_bf(a0), ld_frag(r0b + off), acc0, 0, 0, 0);
        a0 = a1; a1 = an;
    }

    // prefetch GEMM2 A-frags (global, independent of LDS); only waves 0..4
    uint4 a20 = {}, a21 = {}, a22 = {}, a23 = {};
    if (w < 5) {
        const uint4* A2p = (const uint4*)(wsW + WS_W1F_U32) + w * 64 + lane;
        a20 = A2p[0]; a21 = A2p[320]; a22 = A2p[640]; a23 = A2p[960];
    }

    __syncthreads();   // all smF reads done; safe to alias smHT

    // ---- h: bias + leaky, packed o-pairs -> smHT[hwlocal*68 + o/2] ----
    #pragma unroll
    for (int rp = 0; rp < 2; ++rp) {
        int o0 = w * 16 + quad * 4 + 2 * rp;
        float v0 = acc0[2 * rp]     + B1[o0];
        float v1 = acc0[2 * rp + 1] + B1[o0 + 1];
        v0 = v0 > 0.f ? v0 : 0.01f * v0;
        v1 = v1 > 0.f ? v1 : 0.01f * v1;
        smHT[m16 * 68 + (o0 >> 1)] = pack2bf(v0, v1);
    }
    __syncthreads();   // smHT ready

    // ---- GEMM2: 5 m-tiles x 1 n-tile; waves 0..4, waves 5..7 skip to IoU ----
    if (w < 5) {
        f32x4 c2 = (f32x4)(0.f);
        const unsigned* Bb = smHT + m16 * 68 + quad * 4;
        c2 = __builtin_amdgcn_mfma_f32_16x16x32_bf16(as_bf(a20), ld_frag(Bb +  0), c2, 0, 0, 0);
        c2 = __builtin_amdgcn_mfma_f32_16x16x32_bf16(as_bf(a21), ld_frag(Bb + 16), c2, 0, 0, 0);
        c2 = __builtin_amdgcn_mfma_f32_16x16x32_bf16(as_bf(a22), ld_frag(Bb + 32), c2, 0, 0, 0);
        c2 = __builtin_amdgcn_mfma_f32_16x16x32_bf16(as_bf(a23), ld_frag(Bb + 48), c2, 0, 0, 0);
        int hw = hw0 + m16;
        if (hw < HW_) {
            #pragma unroll
            for (int r = 0; r < 4; ++r) {
                int o2 = w * 16 + quad * 4 + r;
                if (o2 >= OUTD_) continue;
                float aa = c2[r] + B2[o2];
                unsigned dst; float val;
                if (o2 < 36) {
                    int an9 = o2 >> 2, kk = o2 & 3;
                    val = (kk < 2) ? (sigmoidf_(aa) - 0.5f) : aa;
                    dst = OFFS_OFF + b * 1764 + an9 * 196 + kk * 49 + hw;
                } else if (o2 < 45) {
                    val = sigmoidf_(aa);
                    dst = CONF_OFF + b * 441 + (o2 - 36) * 49 + hw;
                } else {
                    val = aa;
                    dst = CLS_OFF + b * 980 + (o2 - 45) * 49 + hw;
                }
                out[dst] = val;
            }
        }
    }

    // ---- IoU: wave-uniform p, g = lane (<40), unrolled, coalesced stores ----
    {
        int gl = (lane < NGT_) ? lane : 0;
        const float* gb = bbox + b * 200 + gl * 5;
        float gx1 = gb[0], gy1 = gb[1], gx2 = gb[2], gy2 = gb[3];
        float gA = (gx2 - gx1) * (gy2 - gy1);
        const int pstart = (qtr * NP_) >> 2;
        const int pend   = ((qtr + 1) * NP_) >> 2;
        #pragma unroll 4
        for (int p = pstart + w; p < pend; p += 8) {
            int a9 = p / 49, r = p - a9 * 49;
            float2 ct = *(const float2*)(grd + b * 98 + 2 * r);
            float hx = anc[2 * a9] * 0.5f,  hy = anc[2 * a9 + 1] * 0.5f;
            float px1 = ct.x - hx, py1 = ct.y - hy, px2 = ct.x + hx, py2 = ct.y + hy;
            float pA = (px2 - px1) * (py2 - py1);
            float legal = (fminf(fminf(px1, py1), fminf(px2, py2)) > 0.f) ? 1.f : 0.f;
            float tlx = fmaxf(px1, gx1), tly = fmaxf(py1, gy1);
            float brx = fminf(px2, gx2), bry = fminf(py2, gy2);
            float dx = fmaxf(brx - tlx, 0.f), dy = fmaxf(bry - tly, 0.f);
            float inter = dx * dy * legal;
            float iou = inter / (gA + pA - inter);
            if (lane < NGT_)
                out[IOU_OFF + b * (NP_ * NGT_) + p * 40 + lane] = iou;
        }
    }
}

extern "C" void kernel_launch(void* const* d_in, const int* in_sizes, int n_in,
                              void* d_out, int out_size, void* d_ws, size_t ws_size,
                              hipStream_t stream) {
    const float* F  = (const float*)d_in[0];
    const float* G  = (const float*)d_in[1];
    const float* BB = (const float*)d_in[2];
    const float* AN = (const float*)d_in[3];
    const float* W1 = (const float*)d_in[4];
    const float* B1 = (const float*)d_in[5];
    const float* W2 = (const float*)d_in[6];
    const float* B2 = (const float*)d_in[7];
    float* out = (float*)d_out;
    unsigned* wsu = (unsigned*)d_ws;

    prep_w<<<340, 256, 0, stream>>>(W1, W2, wsu);
    fused_main<<<1024, 512, 0, stream>>>(F, G, BB, AN, wsu, B1, B2, out);
}

// Round 2
// 135.616 us; speedup vs baseline: 1.0739x; 1.0739x over previous
//
#include <hip/hip_runtime.h>

// SingleStageDetector, R11 = R9 geometry (512 blocks = image x half, 32 hw
// rows, 2 accumulators) + chunked double-buffered staging + conflict-free
// b128 staging writes.
//   - F staged in 5 chunks of 256 channels; LDS = 2 x 16 KB buffers; loads
//     for chunk c+1 issued BEFORE compute of chunk c (HBM latency hidden
//     under MFMA/ds_read), one barrier per chunk.
//   - staging write = ds_write_b128 per (row, slot): 8-lane groups span all
//     32 banks (slot ^ (row&7) swizzle) -> no bank conflicts (R9/R10 had
//     2.4M/1.75M conflict-cycles from u32 staging writes hitting 8 banks).
//   - K-loop, h-phase, GEMM2, epilogue, IoU identical to proven R9.
// prep_w unchanged: W1/W2 -> fragment-ready bf16 images in ws.

#define CIN_  1280
#define HW_   49
#define HID_  128
#define OUTD_ 65
#define NGT_  40
#define NP_   441

// flat output offsets (elements), reference return order
#define CONF_OFF 0
#define OFFS_OFF 112896   // 256*9*49
#define CLS_OFF  564480   // + 256*9*4*49
#define IOU_OFF  815360   // + 256*20*49 ; total 5,331,200

// ws layout (u32): W1f frags ((K32*8+mt)*64+lane)*4+sub, then W2f frags
#define WS_W1F_U32 81920u
#define WS_W2F_U32 5120u

typedef __bf16 bf16x8 __attribute__((ext_vector_type(8)));
typedef float  f32x4  __attribute__((ext_vector_type(4)));

__device__ __forceinline__ unsigned pack2bf(float lo, float hi) {
    unsigned a = __float_as_uint(lo);
    unsigned b = __float_as_uint(hi);
    a = (a + 0x7FFFu + ((a >> 16) & 1u)) >> 16;   // RNE f32->bf16
    b = (b + 0x7FFFu + ((b >> 16) & 1u)) >> 16;
    return a | (b << 16);
}
__device__ __forceinline__ float sigmoidf_(float v) { return 1.f / (1.f + __expf(-v)); }

__device__ __forceinline__ bf16x8 ld_frag(const unsigned* p) {
    union { uint4 u; bf16x8 v; } x;
    x.u = *(const uint4*)p;                       // 16B-aligned ds_read_b128
    return x.v;
}
__device__ __forceinline__ bf16x8 as_bf(uint4 u) {
    union { uint4 u; bf16x8 v; } x; x.u = u; return x.v;
}

// ---------------------------------------------------------------------------
// prep_w: W1 (128,1280) + W2 (65,128) -> fragment-ready bf16 images. (R8.)
// ---------------------------------------------------------------------------
__global__ __launch_bounds__(256) void prep_w(
    const float* __restrict__ W1, const float* __restrict__ W2,
    unsigned* __restrict__ ws)
{
    int X = blockIdx.x * 256 + threadIdx.x;       // 0..87039
    if (X < (int)WS_W1F_U32) {
        int sub = X & 3, lane = (X >> 2) & 63, f = X >> 8;
        int mt = f & 7, K32 = f >> 3;
        int o = mt * 16 + (lane & 15);
        int c = K32 * 32 + (lane >> 4) * 8 + sub * 2;
        float2 v = *(const float2*)(W1 + o * CIN_ + c);
        ws[X] = pack2bf(v.x, v.y);
    } else {
        int Y = X - (int)WS_W1F_U32;              // 0..5119
        int sub = Y & 3, lane = (Y >> 2) & 63, f = Y >> 8;
        int mt2 = f % 5, ks2 = f / 5;
        int o2 = mt2 * 16 + (lane & 15);
        int c = ks2 * 32 + (lane >> 4) * 8 + sub * 2;
        unsigned val = 0;
        if (o2 < OUTD_) {
            float2 v = *(const float2*)(W2 + o2 * HID_ + c);
            val = pack2bf(v.x, v.y);
        }
        ws[WS_W1F_U32 + Y] = val;
    }
}

// ---------------------------------------------------------------------------
// fused_main: block = (b, half). LDS: 2 chunk buffers of 32 rows x 128 u32
// (256 channels as bf16 pairs), XOR swizzle on 16B slots
// (phys_slot = slot ^ (row&7)). smHT (32x68 u32) aliases buffer 0.
// ---------------------------------------------------------------------------
__global__ __launch_bounds__(512, 4) void fused_main(
    const float* __restrict__ F,     // (256,1280,7,7)
    const float* __restrict__ grd,   // (256,7,7,2)
    const float* __restrict__ bbox,  // (256,40,5)
    const float* __restrict__ anc,   // (9,2)
    const unsigned* __restrict__ wsW,
    const float* __restrict__ B1,    // (128,)
    const float* __restrict__ B2,    // (65,)
    float* __restrict__ out)
{
    __shared__ __align__(16) unsigned lds[2 * 32 * 128];   // 32,768 B
    unsigned* smHT = lds;                                  // aliased after K-loop

    const int tid  = threadIdx.x;
    const int b    = blockIdx.x >> 1;
    const int half = blockIdx.x & 1;
    const int lane = tid & 63;
    const int w    = tid >> 6;         // 0..7 = GEMM1 m-tile
    const int quad = lane >> 4;
    const int m16  = lane & 15;
    const int hw0  = half * 32;

    const float* Fb = F + b * (CIN_ * HW_);

    // staging decomposition (per chunk of 256 channels = 32 slots x 32 rows):
    // thread -> row = tid&31 (hw = hw0+row), slots cb0=2*(tid>>5) and cb0+1.
    // Each slot = 8 consecutive channels -> 8 scalar loads -> 4 pack2bf ->
    // one ds_write_b128 at row*128 + ((cb ^ (row&7))<<2).  8-lane write
    // groups hit 8 distinct slot-banks -> conflict-free.
    const int srow = tid & 31;
    const int shw  = hw0 + srow;
    const bool sok = shw < HW_;
    const int cb0  = (tid >> 5) * 2;
    const float* Fs = Fb + shw;        // + ch*49

    float fl[16];
    #define STAGE_ISSUE(c)                                                   \
        {                                                                    \
            _Pragma("unroll")                                                \
            for (int u = 0; u < 2; ++u) {                                    \
                _Pragma("unroll")                                            \
                for (int j = 0; j < 8; ++j) {                                \
                    int ch = (c) * 256 + (cb0 + u) * 8 + j;                  \
                    fl[u * 8 + j] = sok ? Fs[ch * HW_] : 0.f;                \
                }                                                            \
            }                                                                \
        }
    #define STAGE_WRITE(c)                                                   \
        {                                                                    \
            unsigned* dstb = lds + (((c) & 1) << 12) + srow * 128;           \
            _Pragma("unroll")                                                \
            for (int u = 0; u < 2; ++u) {                                    \
                int cb = cb0 + u;                                            \
                uint4 q;                                                     \
                q.x = pack2bf(fl[u * 8 + 0], fl[u * 8 + 1]);                 \
                q.y = pack2bf(fl[u * 8 + 2], fl[u * 8 + 3]);                 \
                q.z = pack2bf(fl[u * 8 + 4], fl[u * 8 + 5]);                 \
                q.w = pack2bf(fl[u * 8 + 6], fl[u * 8 + 7]);                 \
                *(uint4*)(dstb + ((cb ^ (srow & 7)) << 2)) = q;              \
            }                                                                \
        }

    // ---- prologue: stage chunk 0, prime A prefetch ----
    STAGE_ISSUE(0);
    const uint4* Ap = (const uint4*)wsW + w * 64 + lane;   // + K32*8*64
    uint4 a0 = Ap[0];
    uint4 a1 = Ap[512];
    STAGE_WRITE(0);
    __syncthreads();

    // ---- chunked K-loop: 5 chunks x 8 K32-steps, 1 barrier/chunk ----
    const unsigned* r0base = lds + m16 * 128;
    const unsigned* r1base = lds + (16 + m16) * 128;
    const int swz = (m16 & 7);

    f32x4 acc0 = (f32x4)(0.f), acc1 = (f32x4)(0.f);
    int kglob = 0;
    #pragma unroll
    for (int c = 0; c < 5; ++c) {
        if (c < 4) STAGE_ISSUE(c + 1);             // HBM latency hides under compute
        const int boff = (c & 1) << 12;
        #pragma unroll
        for (int kk = 0; kk < 8; ++kk) {
            int kp = kglob + 2; if (kp > 39) kp = 39;
            uint4 an = Ap[kp * 512];               // unconditional: precise vmcnt
            int off = (((kk << 2) + quad) ^ swz) << 2;
            bf16x8 A = as_bf(a0);
            acc0 = __builtin_amdgcn_mfma_f32_16x16x32_bf16(A, ld_frag(r0base + boff + off), acc0, 0, 0, 0);
            acc1 = __builtin_amdgcn_mfma_f32_16x16x32_bf16(A, ld_frag(r1base + boff + off), acc1, 0, 0, 0);
            a0 = a1; a1 = an; ++kglob;
        }
        if (c < 4) STAGE_WRITE(c + 1);
        __syncthreads();
    }

    // prefetch GEMM2 A-frags (global, independent of LDS)
    const int m2a = w % 5, nt2a = w / 5;                   // tile w of 10
    const uint4* A2p = (const uint4*)(wsW + WS_W1F_U32) + m2a * 64 + lane;
    uint4 a20 = A2p[0], a21 = A2p[320], a22 = A2p[640], a23 = A2p[960];

    // ---- h: bias + leaky, packed o-pairs -> smHT[hwlocal*68 + o/2] ----
    #pragma unroll
    for (int nt = 0; nt < 2; ++nt) {
        f32x4 ac = nt ? acc1 : acc0;
        int r0 = nt * 16 + m16;
        #pragma unroll
        for (int rp = 0; rp < 2; ++rp) {
            int o0 = w * 16 + quad * 4 + 2 * rp;
            float v0 = ac[2 * rp]     + B1[o0];
            float v1 = ac[2 * rp + 1] + B1[o0 + 1];
            v0 = v0 > 0.f ? v0 : 0.01f * v0;
            v1 = v1 > 0.f ? v1 : 0.01f * v1;
            smHT[r0 * 68 + (o0 >> 1)] = pack2bf(v0, v1);
        }
    }
    __syncthreads();   // smHT ready

    // ---- GEMM2: tile (m2, nt2); wave w -> tile w; waves 0,1 also tiles 8,9 ----
    {
        f32x4 c2 = (f32x4)(0.f);
        const unsigned* Bb = smHT + (nt2a * 16 + m16) * 68 + quad * 4;
        c2 = __builtin_amdgcn_mfma_f32_16x16x32_bf16(as_bf(a20), ld_frag(Bb +  0), c2, 0, 0, 0);
        c2 = __builtin_amdgcn_mfma_f32_16x16x32_bf16(as_bf(a21), ld_frag(Bb + 16), c2, 0, 0, 0);
        c2 = __builtin_amdgcn_mfma_f32_16x16x32_bf16(as_bf(a22), ld_frag(Bb + 32), c2, 0, 0, 0);
        c2 = __builtin_amdgcn_mfma_f32_16x16x32_bf16(as_bf(a23), ld_frag(Bb + 48), c2, 0, 0, 0);
        int hw = hw0 + nt2a * 16 + m16;
        if (hw < HW_) {
            #pragma unroll
            for (int r = 0; r < 4; ++r) {
                int o2 = m2a * 16 + quad * 4 + r;
                if (o2 >= OUTD_) continue;
                float aa = c2[r] + B2[o2];
                unsigned dst; float val;
                if (o2 < 36) {
                    int an9 = o2 >> 2, kk = o2 & 3;
                    val = (kk < 2) ? (sigmoidf_(aa) - 0.5f) : aa;
                    dst = OFFS_OFF + b * 1764 + an9 * 196 + kk * 49 + hw;
                } else if (o2 < 45) {
                    val = sigmoidf_(aa);
                    dst = CONF_OFF + b * 441 + (o2 - 36) * 49 + hw;
                } else {
                    val = aa;
                    dst = CLS_OFF + b * 980 + (o2 - 45) * 49 + hw;
                }
                out[dst] = val;
            }
        }
    }
    if (w < 2) {       // tiles 8,9: m2 = 3+w, nt2 = 1
        const int m2b = 3 + w;
        const uint4* A3p = (const uint4*)(wsW + WS_W1F_U32) + m2b * 64 + lane;
        uint4 b20 = A3p[0], b21 = A3p[320], b22 = A3p[640], b23 = A3p[960];
        f32x4 c2 = (f32x4)(0.f);
        const unsigned* Bb = smHT + (16 + m16) * 68 + quad * 4;
        c2 = __builtin_amdgcn_mfma_f32_16x16x32_bf16(as_bf(b20), ld_frag(Bb +  0), c2, 0, 0, 0);
        c2 = __builtin_amdgcn_mfma_f32_16x16x32_bf16(as_bf(b21), ld_frag(Bb + 16), c2, 0, 0, 0);
        c2 = __builtin_amdgcn_mfma_f32_16x16x32_bf16(as_bf(b22), ld_frag(Bb + 32), c2, 0, 0, 0);
        c2 = __builtin_amdgcn_mfma_f32_16x16x32_bf16(as_bf(b23), ld_frag(Bb + 48), c2, 0, 0, 0);
        int hw = hw0 + 16 + m16;
        if (hw < HW_) {
            #pragma unroll
            for (int r = 0; r < 4; ++r) {
                int o2 = m2b * 16 + quad * 4 + r;
                if (o2 >= OUTD_) continue;
                float aa = c2[r] + B2[o2];
                unsigned dst; float val;
                if (o2 < 36) {
                    int an9 = o2 >> 2, kk = o2 & 3;
                    val = (kk < 2) ? (sigmoidf_(aa) - 0.5f) : aa;
                    dst = OFFS_OFF + b * 1764 + an9 * 196 + kk * 49 + hw;
                } else if (o2 < 45) {
                    val = sigmoidf_(aa);
                    dst = CONF_OFF + b * 441 + (o2 - 36) * 49 + hw;
                } else {
                    val = aa;
                    dst = CLS_OFF + b * 980 + (o2 - 45) * 49 + hw;
                }
                out[dst] = val;
            }
        }
    }

    // ---- IoU: wave-uniform p, g = lane (<40), unrolled, coalesced stores ----
    {
        int gl = (lane < NGT_) ? lane : 0;
        const float* gb = bbox + b * 200 + gl * 5;
        float gx1 = gb[0], gy1 = gb[1], gx2 = gb[2], gy2 = gb[3];
        float gA = (gx2 - gx1) * (gy2 - gy1);
        const int pstart = half ? 221 : 0;
        const int pend   = half ? NP_ : 221;
        #pragma unroll 4
        for (int p = pstart + w; p < pend; p += 8) {
            int a9 = p / 49, r = p - a9 * 49;
            float2 ct = *(const float2*)(grd + b * 98 + 2 * r);
            float hx = anc[2 * a9] * 0.5f,  hy = anc[2 * a9 + 1] * 0.5f;
            float px1 = ct.x - hx, py1 = ct.y - hy, px2 = ct.x + hx, py2 = ct.y + hy;
            float pA = (px2 - px1) * (py2 - py1);
            float legal = (fminf(fminf(px1, py1), fminf(px2, py2)) > 0.f) ? 1.f : 0.f;
            float tlx = fmaxf(px1, gx1), tly = fmaxf(py1, gy1);
            float brx = fminf(px2, gx2), bry = fminf(py2, gy2);
            float dx = fmaxf(brx - tlx, 0.f), dy = fmaxf(bry - tly, 0.f);
            float inter = dx * dy * legal;
            float iou = inter / (gA + pA - inter);
            if (lane < NGT_)
                out[IOU_OFF + b * (NP_ * NGT_) + p * 40 + lane] = iou;
        }
    }
}

extern "C" void kernel_launch(void* const* d_in, const int* in_sizes, int n_in,
                              void* d_out, int out_size, void* d_ws, size_t ws_size,
                              hipStream_t stream) {
    const float* F  = (const float*)d_in[0];
    const float* G  = (const float*)d_in[1];
    const float* BB = (const float*)d_in[2];
    const float* AN = (const float*)d_in[3];
    const float* W1 = (const float*)d_in[4];
    const float* B1 = (const float*)d_in[5];
    const float* W2 = (const float*)d_in[6];
    const float* B2 = (const float*)d_in[7];
    float* out = (float*)d_out;
    unsigned* wsu = (unsigned*)d_ws;

    prep_w<<<340, 256, 0, stream>>>(W1, W2, wsu);
    fused_main<<<512, 512, 0, stream>>>(F, G, BB, AN, wsu, B1, B2, out);
}

// Round 4
// 131.878 us; speedup vs baseline: 1.1044x; 1.0283x over previous
//
#include <hip/hip_runtime.h>

// SingleStageDetector, R13 = R12 resubmitted (R12 bench was an infra failure:
// container acquisition died twice; no kernel result was produced).
//   - 2-ahead register-held staging: prologue issues chunks 0,1; loop iter c
//     issues c+2, computes c, writes c+1. Loads get a FULL chunk-period of
//     HBM delivery (R9/R11 gave them only the ~400-cyc compute sliver ->
//     2 TB/s achieved; fill kernel proves 6.3 is available).
//   - full IoU moved into the prologue (independent of staged data): its
//     VALU absorbs chunks 0/1 delivery latency.
//   - exec-masked staging (if sok): no speculative OOB loads, no cndmask
//     per element; pad rows zeroed once per buffer (never rewritten).
//   - pack2bf via __bf16 casts (v_cvt_pk_bf16_f32), __fdividef in IoU.
//   - K-loop, h-phase, GEMM2, epilogue unchanged (proven R9/R11).
// prep_w unchanged: W1/W2 -> fragment-ready bf16 images in ws.

#define CIN_  1280
#define HW_   49
#define HID_  128
#define OUTD_ 65
#define NGT_  40
#define NP_   441

// flat output offsets (elements), reference return order
#define CONF_OFF 0
#define OFFS_OFF 112896   // 256*9*49
#define CLS_OFF  564480   // + 256*9*4*49
#define IOU_OFF  815360   // + 256*20*49 ; total 5,331,200

// ws layout (u32): W1f frags ((K32*8+mt)*64+lane)*4+sub, then W2f frags
#define WS_W1F_U32 81920u
#define WS_W2F_U32 5120u

typedef __bf16 bf16x8 __attribute__((ext_vector_type(8)));
typedef float  f32x4  __attribute__((ext_vector_type(4)));

__device__ __forceinline__ unsigned pack2bf(float lo, float hi) {
    unsigned short a = __builtin_bit_cast(unsigned short, (__bf16)lo);
    unsigned short b = __builtin_bit_cast(unsigned short, (__bf16)hi);
    return (unsigned)a | ((unsigned)b << 16);   // compiler: v_cvt_pk_bf16_f32
}
__device__ __forceinline__ float sigmoidf_(float v) { return 1.f / (1.f + __expf(-v)); }

__device__ __forceinline__ bf16x8 ld_frag(const unsigned* p) {
    union { uint4 u; bf16x8 v; } x;
    x.u = *(const uint4*)p;                       // 16B-aligned ds_read_b128
    return x.v;
}
__device__ __forceinline__ bf16x8 as_bf(uint4 u) {
    union { uint4 u; bf16x8 v; } x; x.u = u; return x.v;
}

// ---------------------------------------------------------------------------
// prep_w: W1 (128,1280) + W2 (65,128) -> fragment-ready bf16 images. (R8.)
// ---------------------------------------------------------------------------
__global__ __launch_bounds__(256) void prep_w(
    const float* __restrict__ W1, const float* __restrict__ W2,
    unsigned* __restrict__ ws)
{
    int X = blockIdx.x * 256 + threadIdx.x;       // 0..87039
    if (X < (int)WS_W1F_U32) {
        int sub = X & 3, lane = (X >> 2) & 63, f = X >> 8;
        int mt = f & 7, K32 = f >> 3;
        int o = mt * 16 + (lane & 15);
        int c = K32 * 32 + (lane >> 4) * 8 + sub * 2;
        float2 v = *(const float2*)(W1 + o * CIN_ + c);
        ws[X] = pack2bf(v.x, v.y);
    } else {
        int Y = X - (int)WS_W1F_U32;              // 0..5119
        int sub = Y & 3, lane = (Y >> 2) & 63, f = Y >> 8;
        int mt2 = f % 5, ks2 = f / 5;
        int o2 = mt2 * 16 + (lane & 15);
        int c = ks2 * 32 + (lane >> 4) * 8 + sub * 2;
        unsigned val = 0;
        if (o2 < OUTD_) {
            float2 v = *(const float2*)(W2 + o2 * HID_ + c);
            val = pack2bf(v.x, v.y);
        }
        ws[WS_W1F_U32 + Y] = val;
    }
}

// ---------------------------------------------------------------------------
// fused_main: block = (b, half). LDS: 2 chunk buffers of 32 rows x 128 u32
// (256 channels as bf16 pairs), XOR swizzle on 16B slots
// (phys_slot = slot ^ (row&7)). smHT (32x68 u32) aliases buffer 0.
// ---------------------------------------------------------------------------
__global__ __launch_bounds__(512, 4) void fused_main(
    const float* __restrict__ F,     // (256,1280,7,7)
    const float* __restrict__ grd,   // (256,7,7,2)
    const float* __restrict__ bbox,  // (256,40,5)
    const float* __restrict__ anc,   // (9,2)
    const unsigned* __restrict__ wsW,
    const float* __restrict__ B1,    // (128,)
    const float* __restrict__ B2,    // (65,)
    float* __restrict__ out)
{
    __shared__ __align__(16) unsigned lds[2 * 32 * 128];   // 32,768 B
    unsigned* smHT = lds;                                  // aliased after K-loop

    const int tid  = threadIdx.x;
    const int b    = blockIdx.x >> 1;
    const int half = blockIdx.x & 1;
    const int lane = tid & 63;
    const int w    = tid >> 6;         // 0..7 = GEMM1 m-tile
    const int quad = lane >> 4;
    const int m16  = lane & 15;
    const int hw0  = half * 32;

    const float* Fb = F + b * (CIN_ * HW_);

    // staging decomposition (per chunk of 256 channels = 32 slots x 32 rows):
    // thread -> row = tid&31 (hw = hw0+row), slots cb0=2*(tid>>5), cb0+1.
    // Slot = 8 consecutive channels -> 8 loads -> 4 pack2bf -> ds_write_b128
    // at row*128 + ((cb ^ (row&7))<<2).  Even bank spread, conflict-free.
    const int srow = tid & 31;
    const int shw  = hw0 + srow;
    const bool sok = shw < HW_;
    const int cb0  = (tid >> 5) * 2;
    const float* Fs = Fb + shw;        // + ch*49

    float fl[2][16];                   // chunk c lives in fl[c&1]
    #define STAGE_ISSUE(c)                                                   \
        if (sok) {                                                           \
            _Pragma("unroll")                                                \
            for (int u = 0; u < 2; ++u) {                                    \
                _Pragma("unroll")                                            \
                for (int j = 0; j < 8; ++j) {                                \
                    int ch = (c) * 256 + (cb0 + u) * 8 + j;                  \
                    fl[(c) & 1][u * 8 + j] = Fs[ch * HW_];                   \
                }                                                            \
            }                                                                \
        }
    #define STAGE_WRITE(c)                                                   \
        if (sok) {                                                           \
            unsigned* dstb = lds + (((c) & 1) << 12) + srow * 128;           \
            _Pragma("unroll")                                                \
            for (int u = 0; u < 2; ++u) {                                    \
                int cb = cb0 + u;                                            \
                uint4 q;                                                     \
                q.x = pack2bf(fl[(c) & 1][u * 8 + 0], fl[(c) & 1][u * 8 + 1]); \
                q.y = pack2bf(fl[(c) & 1][u * 8 + 2], fl[(c) & 1][u * 8 + 3]); \
                q.z = pack2bf(fl[(c) & 1][u * 8 + 4], fl[(c) & 1][u * 8 + 5]); \
                q.w = pack2bf(fl[(c) & 1][u * 8 + 6], fl[(c) & 1][u * 8 + 7]); \
                *(uint4*)(dstb + ((cb ^ (srow & 7)) << 2)) = q;              \
            }                                                                \
        }

    // ---- prologue: zero pad rows (both buffers), issue chunks 0+1, IoU ----
    if (!sok) {                        // only half=1 blocks have pad rows
        uint4 z = {0u, 0u, 0u, 0u};
        #pragma unroll
        for (int bf = 0; bf < 2; ++bf) {
            unsigned* dstb = lds + (bf << 12) + srow * 128;
            *(uint4*)(dstb + (((cb0    ) ^ (srow & 7)) << 2)) = z;
            *(uint4*)(dstb + (((cb0 + 1) ^ (srow & 7)) << 2)) = z;
        }
    }
    STAGE_ISSUE(0);
    const uint4* Ap = (const uint4*)wsW + w * 64 + lane;   // + K32*8*64
    uint4 a0 = Ap[0];
    uint4 a1 = Ap[512];
    STAGE_ISSUE(1);

    // ---- IoU (independent of staged data; absorbs chunk 0/1 delivery) ----
    {
        int gl = (lane < NGT_) ? lane : 0;
        const float* gb = bbox + b * 200 + gl * 5;
        float gx1 = gb[0], gy1 = gb[1], gx2 = gb[2], gy2 = gb[3];
        float gA = (gx2 - gx1) * (gy2 - gy1);
        const int pstart = half ? 221 : 0;
        const int pend   = half ? NP_ : 221;
        #pragma unroll 4
        for (int p = pstart + w; p < pend; p += 8) {
            int a9 = p / 49, r = p - a9 * 49;
            float2 ct = *(const float2*)(grd + b * 98 + 2 * r);
            float hx = anc[2 * a9] * 0.5f,  hy = anc[2 * a9 + 1] * 0.5f;
            float px1 = ct.x - hx, py1 = ct.y - hy, px2 = ct.x + hx, py2 = ct.y + hy;
            float pA = (px2 - px1) * (py2 - py1);
            float legal = (fminf(fminf(px1, py1), fminf(px2, py2)) > 0.f) ? 1.f : 0.f;
            float tlx = fmaxf(px1, gx1), tly = fmaxf(py1, gy1);
            float brx = fminf(px2, gx2), bry = fminf(py2, gy2);
            float dx = fmaxf(brx - tlx, 0.f), dy = fmaxf(bry - tly, 0.f);
            float inter = dx * dy * legal;
            float iou = __fdividef(inter, gA + pA - inter);
            if (lane < NGT_)
                out[IOU_OFF + b * (NP_ * NGT_) + p * 40 + lane] = iou;
        }
    }

    STAGE_WRITE(0);
    __syncthreads();

    // ---- chunked K-loop: 5 chunks x 8 K32-steps, 2-ahead issue ----
    const unsigned* r0base = lds + m16 * 128;
    const unsigned* r1base = lds + (16 + m16) * 128;
    const int swz = (m16 & 7);

    f32x4 acc0 = (f32x4)(0.f), acc1 = (f32x4)(0.f);
    int kglob = 0;
    #pragma unroll
    for (int c = 0; c < 5; ++c) {
        if (c < 3) STAGE_ISSUE(c + 2);             // full chunk-period head start
        const int boff = (c & 1) << 12;
        #pragma unroll
        for (int kk = 0; kk < 8; ++kk) {
            int kp = kglob + 2; if (kp > 39) kp = 39;
            uint4 an = Ap[kp * 512];               // unconditional: precise vmcnt
            int off = (((kk << 2) + quad) ^ swz) << 2;
            bf16x8 A = as_bf(a0);
            acc0 = __builtin_amdgcn_mfma_f32_16x16x32_bf16(A, ld_frag(r0base + boff + off), acc0, 0, 0, 0);
            acc1 = __builtin_amdgcn_mfma_f32_16x16x32_bf16(A, ld_frag(r1base + boff + off), acc1, 0, 0, 0);
            a0 = a1; a1 = an; ++kglob;
        }
        if (c < 4) STAGE_WRITE(c + 1);
        __syncthreads();
    }

    // prefetch GEMM2 A-frags (global, independent of LDS)
    const int m2a = w % 5, nt2a = w / 5;                   // tile w of 10
    const uint4* A2p = (const uint4*)(wsW + WS_W1F_U32) + m2a * 64 + lane;
    uint4 a20 = A2p[0], a21 = A2p[320], a22 = A2p[640], a23 = A2p[960];

    // ---- h: bias + leaky, packed o-pairs -> smHT[hwlocal*68 + o/2] ----
    #pragma unroll
    for (int nt = 0; nt < 2; ++nt) {
        f32x4 ac = nt ? acc1 : acc0;
        int r0 = nt * 16 + m16;
        #pragma unroll
        for (int rp = 0; rp < 2; ++rp) {
            int o0 = w * 16 + quad * 4 + 2 * rp;
            float v0 = ac[2 * rp]     + B1[o0];
            float v1 = ac[2 * rp + 1] + B1[o0 + 1];
            v0 = v0 > 0.f ? v0 : 0.01f * v0;
            v1 = v1 > 0.f ? v1 : 0.01f * v1;
            smHT[r0 * 68 + (o0 >> 1)] = pack2bf(v0, v1);
        }
    }
    __syncthreads();   // smHT ready

    // ---- GEMM2: tile (m2, nt2); wave w -> tile w; waves 0,1 also tiles 8,9 ----
    {
        f32x4 c2 = (f32x4)(0.f);
        const unsigned* Bb = smHT + (nt2a * 16 + m16) * 68 + quad * 4;
        c2 = __builtin_amdgcn_mfma_f32_16x16x32_bf16(as_bf(a20), ld_frag(Bb +  0), c2, 0, 0, 0);
        c2 = __builtin_amdgcn_mfma_f32_16x16x32_bf16(as_bf(a21), ld_frag(Bb + 16), c2, 0, 0, 0);
        c2 = __builtin_amdgcn_mfma_f32_16x16x32_bf16(as_bf(a22), ld_frag(Bb + 32), c2, 0, 0, 0);
        c2 = __builtin_amdgcn_mfma_f32_16x16x32_bf16(as_bf(a23), ld_frag(Bb + 48), c2, 0, 0, 0);
        int hw = hw0 + nt2a * 16 + m16;
        if (hw < HW_) {
            #pragma unroll
            for (int r = 0; r < 4; ++r) {
                int o2 = m2a * 16 + quad * 4 + r;
                if (o2 >= OUTD_) continue;
                float aa = c2[r] + B2[o2];
                unsigned dst; float val;
                if (o2 < 36) {
                    int an9 = o2 >> 2, kk = o2 & 3;
                    val = (kk < 2) ? (sigmoidf_(aa) - 0.5f) : aa;
                    dst = OFFS_OFF + b * 1764 + an9 * 196 + kk * 49 + hw;
                } else if (o2 < 45) {
                    val = sigmoidf_(aa);
                    dst = CONF_OFF + b * 441 + (o2 - 36) * 49 + hw;
                } else {
                    val = aa;
                    dst = CLS_OFF + b * 980 + (o2 - 45) * 49 + hw;
                }
                out[dst] = val;
            }
        }
    }
    if (w < 2) {       // tiles 8,9: m2 = 3+w, nt2 = 1
        const int m2b = 3 + w;
        const uint4* A3p = (const uint4*)(wsW + WS_W1F_U32) + m2b * 64 + lane;
        uint4 b20 = A3p[0], b21 = A3p[320], b22 = A3p[640], b23 = A3p[960];
        f32x4 c2 = (f32x4)(0.f);
        const unsigned* Bb = smHT + (16 + m16) * 68 + quad * 4;
        c2 = __builtin_amdgcn_mfma_f32_16x16x32_bf16(as_bf(b20), ld_frag(Bb +  0), c2, 0, 0, 0);
        c2 = __builtin_amdgcn_mfma_f32_16x16x32_bf16(as_bf(b21), ld_frag(Bb + 16), c2, 0, 0, 0);
        c2 = __builtin_amdgcn_mfma_f32_16x16x32_bf16(as_bf(b22), ld_frag(Bb + 32), c2, 0, 0, 0);
        c2 = __builtin_amdgcn_mfma_f32_16x16x32_bf16(as_bf(b23), ld_frag(Bb + 48), c2, 0, 0, 0);
        int hw = hw0 + 16 + m16;
        if (hw < HW_) {
            #pragma unroll
            for (int r = 0; r < 4; ++r) {
                int o2 = m2b * 16 + quad * 4 + r;
                if (o2 >= OUTD_) continue;
                float aa = c2[r] + B2[o2];
                unsigned dst; float val;
                if (o2 < 36) {
                    int an9 = o2 >> 2, kk = o2 & 3;
                    val = (kk < 2) ? (sigmoidf_(aa) - 0.5f) : aa;
                    dst = OFFS_OFF + b * 1764 + an9 * 196 + kk * 49 + hw;
                } else if (o2 < 45) {
                    val = sigmoidf_(aa);
                    dst = CONF_OFF + b * 441 + (o2 - 36) * 49 + hw;
                } else {
                    val = aa;
                    dst = CLS_OFF + b * 980 + (o2 - 45) * 49 + hw;
                }
                out[dst] = val;
            }
        }
    }
}

extern "C" void kernel_launch(void* const* d_in, const int* in_sizes, int n_in,
                              void* d_out, int out_size, void* d_ws, size_t ws_size,
                              hipStream_t stream) {
    const float* F  = (const float*)d_in[0];
    const float* G  = (const float*)d_in[1];
    const float* BB = (const float*)d_in[2];
    const float* AN = (const float*)d_in[3];
    const float* W1 = (const float*)d_in[4];
    const float* B1 = (const float*)d_in[5];
    const float* W2 = (const float*)d_in[6];
    const float* B2 = (const float*)d_in[7];
    float* out = (float*)d_out;
    unsigned* wsu = (unsigned*)d_ws;

    prep_w<<<340, 256, 0, stream>>>(W1, W2, wsu);
    fused_main<<<512, 512, 0, stream>>>(F, G, BB, AN, wsu, B1, B2, out);
}